// Round 3
// baseline (1389.364 us; speedup 1.0000x reference)
//
#include <hip/hip_runtime.h>
#include <stdint.h>

// AttractorDynamics: sigma = iterate(tanh(drive + (sigma @ J^T)/tau), 10)
// B=16384, M=1024, A=512, tau=0.1, sigma0=0.
// R3: SINGLE fused kernel. Each block owns a 64-row stripe:
//   phase 1: drive = x@W^T + b (3-term hi/lo split), kept in 128 f32 REGS.
//   phase 2: 10 settling steps entirely in-block; sigma lives in LDS (64KB,
//            XOR-granule swizzle); J hi/lo B-frags read DIRECT from L2.
// No per-step global sigma/drive traffic. Rows independent => no grid sync.

#define B_DIM 16384
#define M_DIM 1024
#define A_DIM 512

typedef short bf16x8 __attribute__((ext_vector_type(8)));
typedef float f32x4 __attribute__((ext_vector_type(4)));

__device__ __forceinline__ unsigned short f2bf(float f) {
  unsigned int u = __float_as_uint(f);
  unsigned int r = (u + 0x7FFFu + ((u >> 16) & 1u)) >> 16;  // RNE
  return (unsigned short)r;
}
__device__ __forceinline__ float bf2f(unsigned short s) {
  return __uint_as_float(((unsigned int)s) << 16);
}
__device__ __forceinline__ float fast_tanh(float x) {
  float t = __expf(2.0f * x);
  return fmaf(-2.0f, __builtin_amdgcn_rcpf(t + 1.0f), 1.0f);
}

// ---- prep: split fp32 -> bf16 hi + bf16 lo (optionally pre-scaled) ----
__global__ void split_kernel(const float* __restrict__ src,
                             unsigned short* __restrict__ hi,
                             unsigned short* __restrict__ lo,
                             int n, float scale) {
  int i = blockIdx.x * 256 + threadIdx.x;
  if (i < n) {
    float v = src[i] * scale;
    unsigned short h = f2bf(v);
    hi[i] = h;
    lo[i] = f2bf(v - bf2f(h));
  }
}

// sigma LDS layout: row-major 64x512 bf16, 16B granules XOR-swizzled:
// phys_granule = (col>>3) ^ (row&7). A-frag ds_read_b128 is conflict-free.
__global__ __launch_bounds__(256) void fused_kernel(
    const float* __restrict__ x, const unsigned short* __restrict__ Whi,
    const unsigned short* __restrict__ Wlo, const float* __restrict__ bias,
    const unsigned short* __restrict__ Jhi, const unsigned short* __restrict__ Jlo,
    float* __restrict__ out) {
  __shared__ __align__(16) unsigned short sigL[64 * 512];  // 64 KB

  const int t = threadIdx.x;
  const int bm = blockIdx.x;             // row stripe [bm*64, bm*64+64)
  const int lane = t & 63, w = t >> 6;   // wave w covers cols [w*128, +128)
  const int quad = lane >> 4, l16 = lane & 15;

  f32x4 acc[4][8];        // 4 m-tiles x 8 n-tiles (16x16 each) = 64x128/wave
  float drv[4][8][4];     // drive, full fp32, lives in regs for all 10 steps

  // ---------------- phase 1: drive = x @ W^T + b ----------------
#pragma unroll
  for (int i = 0; i < 4; ++i)
#pragma unroll
    for (int j = 0; j < 8; ++j) acc[i][j] = (f32x4){0.f, 0.f, 0.f, 0.f};

#pragma unroll 2
  for (int c = 0; c < M_DIM / 32; ++c) {  // 32 k-chunks
    bf16x8 xh[4], xl[4];
#pragma unroll
    for (int i = 0; i < 4; ++i) {
      const float* xp =
          x + (size_t)(bm * 64 + i * 16 + l16) * M_DIM + c * 32 + quad * 8;
      float4 a0 = *(const float4*)xp;
      float4 a1 = *(const float4*)(xp + 4);
      float fv[8] = {a0.x, a0.y, a0.z, a0.w, a1.x, a1.y, a1.z, a1.w};
#pragma unroll
      for (int e = 0; e < 8; ++e) {
        unsigned short h = f2bf(fv[e]);
        xh[i][e] = (short)h;
        xl[i][e] = (short)f2bf(fv[e] - bf2f(h));
      }
    }
#pragma unroll
    for (int j = 0; j < 8; ++j) {
      const size_t off =
          (size_t)(w * 128 + j * 16 + l16) * M_DIM + c * 32 + quad * 8;
      bf16x8 bh = *(const bf16x8*)(Whi + off);
      bf16x8 bl = *(const bf16x8*)(Wlo + off);
#pragma unroll
      for (int i = 0; i < 4; ++i) {
        acc[i][j] = __builtin_amdgcn_mfma_f32_16x16x32_bf16(xh[i], bh, acc[i][j], 0, 0, 0);
        acc[i][j] = __builtin_amdgcn_mfma_f32_16x16x32_bf16(xl[i], bh, acc[i][j], 0, 0, 0);
        acc[i][j] = __builtin_amdgcn_mfma_f32_16x16x32_bf16(xh[i], bl, acc[i][j], 0, 0, 0);
      }
    }
  }

#pragma unroll
  for (int j = 0; j < 8; ++j) {
    float bv = bias[w * 128 + j * 16 + l16];
#pragma unroll
    for (int i = 0; i < 4; ++i)
#pragma unroll
      for (int r = 0; r < 4; ++r) drv[i][j][r] = acc[i][j][r] + bv;
  }

  // sigma1 = tanh(drive) -> sigL (swizzled write, C-layout source)
#pragma unroll
  for (int i = 0; i < 4; ++i)
#pragma unroll
    for (int j = 0; j < 8; ++j)
#pragma unroll
      for (int r = 0; r < 4; ++r) {
        int row = i * 16 + quad * 4 + r;
        int col = w * 128 + j * 16 + l16;
        int addr = row * 512 + (((col >> 3) ^ (row & 7)) << 3) + (col & 7);
        sigL[addr] = f2bf(fast_tanh(drv[i][j][r]));
      }
  __syncthreads();

  // ---------------- phase 2: 9 recurrent steps ----------------
  for (int s = 0; s < 9; ++s) {
#pragma unroll
    for (int i = 0; i < 4; ++i)
#pragma unroll
      for (int j = 0; j < 8; ++j) acc[i][j] = (f32x4){0.f, 0.f, 0.f, 0.f};

#pragma unroll
    for (int c = 0; c < A_DIM / 32; ++c) {  // 16 k-chunks
      bf16x8 af[4];
#pragma unroll
      for (int i = 0; i < 4; ++i)
        af[i] = *(const bf16x8*)&sigL[(i * 16 + l16) * 512 +
                                      (((c * 4 + quad) ^ (l16 & 7)) << 3)];
#pragma unroll
      for (int j = 0; j < 8; ++j) {
        const size_t off =
            (size_t)(w * 128 + j * 16 + l16) * A_DIM + c * 32 + quad * 8;
        bf16x8 bh = *(const bf16x8*)(Jhi + off);
        bf16x8 bl = *(const bf16x8*)(Jlo + off);
#pragma unroll
        for (int i = 0; i < 4; ++i) {
          acc[i][j] = __builtin_amdgcn_mfma_f32_16x16x32_bf16(af[i], bh, acc[i][j], 0, 0, 0);
          acc[i][j] = __builtin_amdgcn_mfma_f32_16x16x32_bf16(af[i], bl, acc[i][j], 0, 0, 0);
        }
      }
    }

    if (s < 8) {
      __syncthreads();  // all reads of sigma_t complete before overwrite
#pragma unroll
      for (int i = 0; i < 4; ++i)
#pragma unroll
        for (int j = 0; j < 8; ++j)
#pragma unroll
          for (int r = 0; r < 4; ++r) {
            int row = i * 16 + quad * 4 + r;
            int col = w * 128 + j * 16 + l16;
            int addr = row * 512 + (((col >> 3) ^ (row & 7)) << 3) + (col & 7);
            sigL[addr] = f2bf(fast_tanh(drv[i][j][r] + acc[i][j][r]));
          }
      __syncthreads();
    } else {
      // final step: write fp32 output directly
#pragma unroll
      for (int i = 0; i < 4; ++i)
#pragma unroll
        for (int j = 0; j < 8; ++j)
#pragma unroll
          for (int r = 0; r < 4; ++r) {
            int row = bm * 64 + i * 16 + quad * 4 + r;
            int col = w * 128 + j * 16 + l16;
            out[(size_t)row * A_DIM + col] =
                fast_tanh(drv[i][j][r] + acc[i][j][r]);
          }
    }
  }
}

extern "C" void kernel_launch(void* const* d_in, const int* in_sizes, int n_in,
                              void* d_out, int out_size, void* d_ws, size_t ws_size,
                              hipStream_t stream) {
  const float* x = (const float*)d_in[0];
  const float* W = (const float*)d_in[1];
  const float* b = (const float*)d_in[2];
  const float* J = (const float*)d_in[3];
  float* out = (float*)d_out;

  char* ws = (char*)d_ws;
  unsigned short* Whi = (unsigned short*)(ws);             // 1,048,576 B
  unsigned short* Wlo = (unsigned short*)(ws + 1048576);   // 1,048,576 B
  unsigned short* Jhi = (unsigned short*)(ws + 2097152);   //   524,288 B
  unsigned short* Jlo = (unsigned short*)(ws + 2621440);   // end 3,145,728

  const int nW = A_DIM * M_DIM;
  const int nJ = A_DIM * A_DIM;
  split_kernel<<<(nW + 255) / 256, 256, 0, stream>>>(W, Whi, Wlo, nW, 1.0f);
  split_kernel<<<(nJ + 255) / 256, 256, 0, stream>>>(J, Jhi, Jlo, nJ, 10.0f);

  fused_kernel<<<B_DIM / 64, 256, 0, stream>>>(x, Whi, Wlo, b, Jhi, Jlo, out);
}

// Round 4
// 1028.171 us; speedup vs baseline: 1.3513x; 1.3513x over previous
//
#include <hip/hip_runtime.h>
#include <stdint.h>

// AttractorDynamics: sigma = iterate(tanh(drive + (sigma @ J^T)/tau), 10)
// B=16384, M=1024, A=512, tau=0.1, sigma0=0.
// R4: two kernels.
//  1) drive_kernel (R1 structure): drive = x@W^T + b (3-term hi/lo split) -> ws.
//     Confines all x/W L2 streaming to this kernel.
//  2) settle_kernel: 512 threads (8 waves = 2 waves/SIMD), 256 blocks x 64-row
//     stripes. drive in regs (64 f32/thread), sigma in 64KB XOR-swizzled LDS,
//     J hi/lo streamed from a CLEAN L2 (1.5 MB/XCD resident). All 10 settling
//     steps in one launch; zero per-step global sigma/drive traffic.

#define B_DIM 16384
#define M_DIM 1024
#define A_DIM 512

typedef short bf16x8 __attribute__((ext_vector_type(8)));
typedef float f32x4 __attribute__((ext_vector_type(4)));

__device__ __forceinline__ unsigned short f2bf(float f) {
  unsigned int u = __float_as_uint(f);
  unsigned int r = (u + 0x7FFFu + ((u >> 16) & 1u)) >> 16;  // RNE
  return (unsigned short)r;
}
__device__ __forceinline__ float bf2f(unsigned short s) {
  return __uint_as_float(((unsigned int)s) << 16);
}
__device__ __forceinline__ float fast_tanh(float x) {
  float t = __expf(2.0f * x);
  return fmaf(-2.0f, __builtin_amdgcn_rcpf(t + 1.0f), 1.0f);
}

// ---- prep: split fp32 -> bf16 hi + bf16 lo (optionally pre-scaled) ----
__global__ void split_kernel(const float* __restrict__ src,
                             unsigned short* __restrict__ hi,
                             unsigned short* __restrict__ lo,
                             int n, float scale) {
  int i = blockIdx.x * 256 + threadIdx.x;
  if (i < n) {
    float v = src[i] * scale;
    unsigned short h = f2bf(v);
    hi[i] = h;
    lo[i] = f2bf(v - bf2f(h));
  }
}

// ---- drive GEMM (R1 structure, sigma-store dropped): drive = x@W^T + b ----
__global__ __launch_bounds__(256) void drive_kernel(
    const float* __restrict__ x, const unsigned short* __restrict__ Whi,
    const unsigned short* __restrict__ Wlo, const float* __restrict__ bias,
    float* __restrict__ drive) {
  __shared__ __align__(16) unsigned short Ah[128][40];
  __shared__ __align__(16) unsigned short Al[128][40];
  __shared__ __align__(16) unsigned short Bh[128][40];
  __shared__ __align__(16) unsigned short Bl[128][40];

  const int t = threadIdx.x;
  const int bm = blockIdx.y, bn = blockIdx.x;
  const int row = t >> 1, half = t & 1;
  const int lane = t & 63, wave = t >> 6;
  const int wm = wave >> 1, wn = wave & 1;
  const int quad = lane >> 4, l16 = lane & 15;

  f32x4 acc[4][4] = {};

  const float* xp = x + (size_t)(bm * 128 + row) * M_DIM + half * 16;
  const unsigned short* wh = Whi + (size_t)(bn * 128 + row) * M_DIM + half * 16;
  const unsigned short* wl = Wlo + (size_t)(bn * 128 + row) * M_DIM + half * 16;

  for (int k0 = 0; k0 < M_DIM; k0 += 32) {
    float4 v[4];
#pragma unroll
    for (int q = 0; q < 4; ++q) v[q] = *(const float4*)(xp + k0 + 4 * q);
    unsigned short hiv[16], lov[16];
#pragma unroll
    for (int q = 0; q < 4; ++q) {
      float fv[4] = {v[q].x, v[q].y, v[q].z, v[q].w};
#pragma unroll
      for (int e = 0; e < 4; ++e) {
        unsigned short h = f2bf(fv[e]);
        hiv[4 * q + e] = h;
        lov[4 * q + e] = f2bf(fv[e] - bf2f(h));
      }
    }
    *(uint4*)&Ah[row][half * 16]     = *(uint4*)&hiv[0];
    *(uint4*)&Ah[row][half * 16 + 8] = *(uint4*)&hiv[8];
    *(uint4*)&Al[row][half * 16]     = *(uint4*)&lov[0];
    *(uint4*)&Al[row][half * 16 + 8] = *(uint4*)&lov[8];
    *(uint4*)&Bh[row][half * 16]     = *(const uint4*)(wh + k0);
    *(uint4*)&Bh[row][half * 16 + 8] = *(const uint4*)(wh + k0 + 8);
    *(uint4*)&Bl[row][half * 16]     = *(const uint4*)(wl + k0);
    *(uint4*)&Bl[row][half * 16 + 8] = *(const uint4*)(wl + k0 + 8);
    __syncthreads();

    bf16x8 ah[4], al[4], bh[4], bl[4];
#pragma unroll
    for (int i = 0; i < 4; ++i) {
      ah[i] = *(const bf16x8*)&Ah[wm * 64 + i * 16 + l16][quad * 8];
      al[i] = *(const bf16x8*)&Al[wm * 64 + i * 16 + l16][quad * 8];
    }
#pragma unroll
    for (int j = 0; j < 4; ++j) {
      bh[j] = *(const bf16x8*)&Bh[wn * 64 + j * 16 + l16][quad * 8];
      bl[j] = *(const bf16x8*)&Bl[wn * 64 + j * 16 + l16][quad * 8];
    }
#pragma unroll
    for (int i = 0; i < 4; ++i)
#pragma unroll
      for (int j = 0; j < 4; ++j) {
        acc[i][j] = __builtin_amdgcn_mfma_f32_16x16x32_bf16(ah[i], bh[j], acc[i][j], 0, 0, 0);
        acc[i][j] = __builtin_amdgcn_mfma_f32_16x16x32_bf16(ah[i], bl[j], acc[i][j], 0, 0, 0);
        acc[i][j] = __builtin_amdgcn_mfma_f32_16x16x32_bf16(al[i], bh[j], acc[i][j], 0, 0, 0);
      }
    __syncthreads();
  }

#pragma unroll
  for (int i = 0; i < 4; ++i)
#pragma unroll
    for (int j = 0; j < 4; ++j) {
      int gcol = bn * 128 + wn * 64 + j * 16 + l16;
      float bv = bias[gcol];
#pragma unroll
      for (int r = 0; r < 4; ++r) {
        int grow = bm * 128 + wm * 64 + i * 16 + quad * 4 + r;
        drive[(size_t)grow * A_DIM + gcol] = acc[i][j][r] + bv;
      }
    }
}

// ---- settle: 10 steps fused. sigma in LDS (XOR granule swizzle), drive in
// regs, J hi/lo streamed from L2. Block = 512 thr (8 waves), 64-row stripe;
// wave w owns cols [w*64, w*64+64). ----
__global__ __launch_bounds__(512, 2) void settle_kernel(
    const float* __restrict__ drive, const unsigned short* __restrict__ Jhi,
    const unsigned short* __restrict__ Jlo, float* __restrict__ out) {
  __shared__ __align__(16) unsigned short sigL[64 * 512];  // 64 KB

  const int t = threadIdx.x;
  const int bm = blockIdx.x;             // rows [bm*64, +64)
  const int lane = t & 63, w = t >> 6;   // 8 waves
  const int quad = lane >> 4, l16 = lane & 15;

  float drv[4][4][4];  // [m-tile][n-tile][reg] = 64 f32, lives all 10 steps
  f32x4 acc[4][4];

  // load drive (one-time, coalesced) and write sigma1 = tanh(drive) to LDS
#pragma unroll
  for (int i = 0; i < 4; ++i)
#pragma unroll
    for (int j = 0; j < 4; ++j) {
      const int col = w * 64 + j * 16 + l16;
#pragma unroll
      for (int r = 0; r < 4; ++r) {
        const int row = i * 16 + quad * 4 + r;
        drv[i][j][r] = drive[(size_t)(bm * 64 + row) * A_DIM + col];
        const int addr =
            row * 512 + (((col >> 3) ^ (row & 7)) << 3) + (col & 7);
        sigL[addr] = f2bf(fast_tanh(drv[i][j][r]));
      }
    }
  __syncthreads();

  for (int s = 0; s < 9; ++s) {
#pragma unroll
    for (int i = 0; i < 4; ++i)
#pragma unroll
      for (int j = 0; j < 4; ++j) acc[i][j] = (f32x4){0.f, 0.f, 0.f, 0.f};

#pragma unroll
    for (int c = 0; c < A_DIM / 32; ++c) {  // 16 k-chunks of 32
      bf16x8 af[4];
#pragma unroll
      for (int i = 0; i < 4; ++i)
        af[i] = *(const bf16x8*)&sigL[(i * 16 + l16) * 512 +
                                      (((c * 4 + quad) ^ (l16 & 7)) << 3)];
#pragma unroll
      for (int j = 0; j < 4; ++j) {
        const size_t off =
            (size_t)(w * 64 + j * 16 + l16) * A_DIM + c * 32 + quad * 8;
        bf16x8 bh = *(const bf16x8*)(Jhi + off);
        bf16x8 bl = *(const bf16x8*)(Jlo + off);
#pragma unroll
        for (int i = 0; i < 4; ++i) {
          acc[i][j] = __builtin_amdgcn_mfma_f32_16x16x32_bf16(af[i], bh, acc[i][j], 0, 0, 0);
          acc[i][j] = __builtin_amdgcn_mfma_f32_16x16x32_bf16(af[i], bl, acc[i][j], 0, 0, 0);
        }
      }
    }

    if (s < 8) {
      __syncthreads();  // all waves done reading sigma_t
#pragma unroll
      for (int i = 0; i < 4; ++i)
#pragma unroll
        for (int j = 0; j < 4; ++j) {
          const int col = w * 64 + j * 16 + l16;
#pragma unroll
          for (int r = 0; r < 4; ++r) {
            const int row = i * 16 + quad * 4 + r;
            const int addr =
                row * 512 + (((col >> 3) ^ (row & 7)) << 3) + (col & 7);
            sigL[addr] = f2bf(fast_tanh(drv[i][j][r] + acc[i][j][r]));
          }
        }
      __syncthreads();
    } else {
#pragma unroll
      for (int i = 0; i < 4; ++i)
#pragma unroll
        for (int j = 0; j < 4; ++j) {
          const int col = w * 64 + j * 16 + l16;
#pragma unroll
          for (int r = 0; r < 4; ++r) {
            const int row = bm * 64 + i * 16 + quad * 4 + r;
            out[(size_t)row * A_DIM + col] =
                fast_tanh(drv[i][j][r] + acc[i][j][r]);
          }
        }
    }
  }
}

extern "C" void kernel_launch(void* const* d_in, const int* in_sizes, int n_in,
                              void* d_out, int out_size, void* d_ws, size_t ws_size,
                              hipStream_t stream) {
  const float* x = (const float*)d_in[0];
  const float* W = (const float*)d_in[1];
  const float* b = (const float*)d_in[2];
  const float* J = (const float*)d_in[3];
  float* out = (float*)d_out;

  char* ws = (char*)d_ws;
  float* drive        = (float*)(ws);                      // 33,554,432 B
  unsigned short* Whi = (unsigned short*)(ws + 33554432);  //  1,048,576 B
  unsigned short* Wlo = (unsigned short*)(ws + 34603008);  //  1,048,576 B
  unsigned short* Jhi = (unsigned short*)(ws + 35651584);  //    524,288 B
  unsigned short* Jlo = (unsigned short*)(ws + 36175872);  // end 36,700,160

  const int nW = A_DIM * M_DIM;
  const int nJ = A_DIM * A_DIM;
  split_kernel<<<(nW + 255) / 256, 256, 0, stream>>>(W, Whi, Wlo, nW, 1.0f);
  split_kernel<<<(nJ + 255) / 256, 256, 0, stream>>>(J, Jhi, Jlo, nJ, 10.0f);

  dim3 grid(A_DIM / 128, B_DIM / 128);  // (4, 128)
  drive_kernel<<<grid, 256, 0, stream>>>(x, Whi, Wlo, b, drive);

  settle_kernel<<<B_DIM / 64, 512, 0, stream>>>(drive, Jhi, Jlo, out);
}

// Round 5
// 1026.801 us; speedup vs baseline: 1.3531x; 1.0013x over previous
//
#include <hip/hip_runtime.h>
#include <stdint.h>

// AttractorDynamics: sigma = iterate(tanh(drive + (sigma @ J^T)/tau), 10)
// B=16384, M=1024, A=512, tau=0.1, sigma0=0.
// R5: settle_kernel despilled. R4's failure: __launch_bounds__(512,2) forced
// 128 VGPRs -> per-step scratch spills (WRITE 317MB) whose streams evicted J
// from L2 (FETCH 1.16GB). Fix: (512,1) budget, drive packed hi/lo bf16 in
// uint32 (32 regs), hoisted J base pointers + imm offsets, manual 1-chunk
// J-frag double buffer. sigma stays in 64KB XOR-swizzled LDS.

#define B_DIM 16384
#define M_DIM 1024
#define A_DIM 512

typedef short bf16x8 __attribute__((ext_vector_type(8)));
typedef float f32x4 __attribute__((ext_vector_type(4)));

__device__ __forceinline__ unsigned short f2bf(float f) {
  unsigned int u = __float_as_uint(f);
  unsigned int r = (u + 0x7FFFu + ((u >> 16) & 1u)) >> 16;  // RNE
  return (unsigned short)r;
}
__device__ __forceinline__ float bf2f(unsigned short s) {
  return __uint_as_float(((unsigned int)s) << 16);
}
__device__ __forceinline__ float fast_tanh(float x) {
  float t = __expf(2.0f * x);
  return fmaf(-2.0f, __builtin_amdgcn_rcpf(t + 1.0f), 1.0f);
}
// pack fp32 as two stacked bf16 (hi + lo), reconstruct with one add
__device__ __forceinline__ unsigned int packf(float v) {
  unsigned short h = f2bf(v);
  unsigned short l = f2bf(v - bf2f(h));
  return ((unsigned int)h << 16) | l;
}
__device__ __forceinline__ float unpackf(unsigned int p) {
  return __uint_as_float(p & 0xFFFF0000u) + __uint_as_float(p << 16);
}

// ---- prep: split fp32 -> bf16 hi + bf16 lo (optionally pre-scaled) ----
__global__ void split_kernel(const float* __restrict__ src,
                             unsigned short* __restrict__ hi,
                             unsigned short* __restrict__ lo,
                             int n, float scale) {
  int i = blockIdx.x * 256 + threadIdx.x;
  if (i < n) {
    float v = src[i] * scale;
    unsigned short h = f2bf(v);
    hi[i] = h;
    lo[i] = f2bf(v - bf2f(h));
  }
}

// ---- drive GEMM (R1 structure): drive = x@W^T + b ----
__global__ __launch_bounds__(256) void drive_kernel(
    const float* __restrict__ x, const unsigned short* __restrict__ Whi,
    const unsigned short* __restrict__ Wlo, const float* __restrict__ bias,
    float* __restrict__ drive) {
  __shared__ __align__(16) unsigned short Ah[128][40];
  __shared__ __align__(16) unsigned short Al[128][40];
  __shared__ __align__(16) unsigned short Bh[128][40];
  __shared__ __align__(16) unsigned short Bl[128][40];

  const int t = threadIdx.x;
  const int bm = blockIdx.y, bn = blockIdx.x;
  const int row = t >> 1, half = t & 1;
  const int lane = t & 63, wave = t >> 6;
  const int wm = wave >> 1, wn = wave & 1;
  const int quad = lane >> 4, l16 = lane & 15;

  f32x4 acc[4][4] = {};

  const float* xp = x + (size_t)(bm * 128 + row) * M_DIM + half * 16;
  const unsigned short* wh = Whi + (size_t)(bn * 128 + row) * M_DIM + half * 16;
  const unsigned short* wl = Wlo + (size_t)(bn * 128 + row) * M_DIM + half * 16;

  for (int k0 = 0; k0 < M_DIM; k0 += 32) {
    float4 v[4];
#pragma unroll
    for (int q = 0; q < 4; ++q) v[q] = *(const float4*)(xp + k0 + 4 * q);
    unsigned short hiv[16], lov[16];
#pragma unroll
    for (int q = 0; q < 4; ++q) {
      float fv[4] = {v[q].x, v[q].y, v[q].z, v[q].w};
#pragma unroll
      for (int e = 0; e < 4; ++e) {
        unsigned short h = f2bf(fv[e]);
        hiv[4 * q + e] = h;
        lov[4 * q + e] = f2bf(fv[e] - bf2f(h));
      }
    }
    *(uint4*)&Ah[row][half * 16]     = *(uint4*)&hiv[0];
    *(uint4*)&Ah[row][half * 16 + 8] = *(uint4*)&hiv[8];
    *(uint4*)&Al[row][half * 16]     = *(uint4*)&lov[0];
    *(uint4*)&Al[row][half * 16 + 8] = *(uint4*)&lov[8];
    *(uint4*)&Bh[row][half * 16]     = *(const uint4*)(wh + k0);
    *(uint4*)&Bh[row][half * 16 + 8] = *(const uint4*)(wh + k0 + 8);
    *(uint4*)&Bl[row][half * 16]     = *(const uint4*)(wl + k0);
    *(uint4*)&Bl[row][half * 16 + 8] = *(const uint4*)(wl + k0 + 8);
    __syncthreads();

    bf16x8 ah[4], al[4], bh[4], bl[4];
#pragma unroll
    for (int i = 0; i < 4; ++i) {
      ah[i] = *(const bf16x8*)&Ah[wm * 64 + i * 16 + l16][quad * 8];
      al[i] = *(const bf16x8*)&Al[wm * 64 + i * 16 + l16][quad * 8];
    }
#pragma unroll
    for (int j = 0; j < 4; ++j) {
      bh[j] = *(const bf16x8*)&Bh[wn * 64 + j * 16 + l16][quad * 8];
      bl[j] = *(const bf16x8*)&Bl[wn * 64 + j * 16 + l16][quad * 8];
    }
#pragma unroll
    for (int i = 0; i < 4; ++i)
#pragma unroll
      for (int j = 0; j < 4; ++j) {
        acc[i][j] = __builtin_amdgcn_mfma_f32_16x16x32_bf16(ah[i], bh[j], acc[i][j], 0, 0, 0);
        acc[i][j] = __builtin_amdgcn_mfma_f32_16x16x32_bf16(ah[i], bl[j], acc[i][j], 0, 0, 0);
        acc[i][j] = __builtin_amdgcn_mfma_f32_16x16x32_bf16(al[i], bh[j], acc[i][j], 0, 0, 0);
      }
    __syncthreads();
  }

#pragma unroll
  for (int i = 0; i < 4; ++i)
#pragma unroll
    for (int j = 0; j < 4; ++j) {
      int gcol = bn * 128 + wn * 64 + j * 16 + l16;
      float bv = bias[gcol];
#pragma unroll
      for (int r = 0; r < 4; ++r) {
        int grow = bm * 128 + wm * 64 + i * 16 + quad * 4 + r;
        drive[(size_t)grow * A_DIM + gcol] = acc[i][j][r] + bv;
      }
    }
}

// ---- settle: 10 steps fused, despilled. 512 thr (8 waves), 64-row stripe;
// wave w owns cols [w*64, +64). sigma in XOR-swizzled LDS; drive packed in
// 32 uint regs; J hi/lo double-buffered from L2. ----
__global__ __launch_bounds__(512, 1) void settle_kernel(
    const float* __restrict__ drive, const unsigned short* __restrict__ Jhi,
    const unsigned short* __restrict__ Jlo, float* __restrict__ out) {
  __shared__ __align__(16) unsigned short sigL[64 * 512];  // 64 KB

  const int t = threadIdx.x;
  const int bm = blockIdx.x;             // rows [bm*64, +64)
  const int lane = t & 63, w = t >> 6;   // 8 waves
  const int quad = lane >> 4, l16 = lane & 15;

  unsigned int drv[4][4][4];  // packed hi/lo bf16 (exact to ~1.5e-5 rel)
  f32x4 acc[4][4];

  // J base pointers per n-tile (constant across steps; k-chunk via imm offset)
  const unsigned short* jhp[4];
  const unsigned short* jlp[4];
#pragma unroll
  for (int j = 0; j < 4; ++j) {
    const size_t base = (size_t)(w * 64 + j * 16 + l16) * A_DIM + quad * 8;
    jhp[j] = Jhi + base;
    jlp[j] = Jlo + base;
  }

  // one-time drive load; sigma1 = tanh(drive) -> LDS
#pragma unroll
  for (int i = 0; i < 4; ++i)
#pragma unroll
    for (int j = 0; j < 4; ++j) {
      const int col = w * 64 + j * 16 + l16;
#pragma unroll
      for (int r = 0; r < 4; ++r) {
        const int row = i * 16 + quad * 4 + r;
        float dv = drive[(size_t)(bm * 64 + row) * A_DIM + col];
        drv[i][j][r] = packf(dv);
        const int addr =
            row * 512 + (((col >> 3) ^ (row & 7)) << 3) + (col & 7);
        sigL[addr] = f2bf(fast_tanh(dv));
      }
    }
  __syncthreads();

  for (int s = 0; s < 9; ++s) {
#pragma unroll
    for (int i = 0; i < 4; ++i)
#pragma unroll
      for (int j = 0; j < 4; ++j) acc[i][j] = (f32x4){0.f, 0.f, 0.f, 0.f};

    bf16x8 bh[4], bl[4];
#pragma unroll
    for (int j = 0; j < 4; ++j) {
      bh[j] = *(const bf16x8*)(jhp[j]);
      bl[j] = *(const bf16x8*)(jlp[j]);
    }

#pragma unroll
    for (int c = 0; c < A_DIM / 32; ++c) {  // 16 k-chunks
      bf16x8 bhn[4], bln[4];
      if (c < 15) {
#pragma unroll
        for (int j = 0; j < 4; ++j) {
          bhn[j] = *(const bf16x8*)(jhp[j] + (c + 1) * 32);  // imm offset
          bln[j] = *(const bf16x8*)(jlp[j] + (c + 1) * 32);
        }
      }
      bf16x8 af[4];
#pragma unroll
      for (int i = 0; i < 4; ++i)
        af[i] = *(const bf16x8*)&sigL[(i * 16 + l16) * 512 +
                                      (((c * 4 + quad) ^ (l16 & 7)) << 3)];
#pragma unroll
      for (int j = 0; j < 4; ++j)
#pragma unroll
        for (int i = 0; i < 4; ++i) {
          acc[i][j] = __builtin_amdgcn_mfma_f32_16x16x32_bf16(af[i], bh[j], acc[i][j], 0, 0, 0);
          acc[i][j] = __builtin_amdgcn_mfma_f32_16x16x32_bf16(af[i], bl[j], acc[i][j], 0, 0, 0);
        }
      if (c < 15) {
#pragma unroll
        for (int j = 0; j < 4; ++j) { bh[j] = bhn[j]; bl[j] = bln[j]; }
      }
    }

    if (s < 8) {
      __syncthreads();  // all waves done reading sigma_t
#pragma unroll
      for (int i = 0; i < 4; ++i)
#pragma unroll
        for (int j = 0; j < 4; ++j) {
          const int col = w * 64 + j * 16 + l16;
#pragma unroll
          for (int r = 0; r < 4; ++r) {
            const int row = i * 16 + quad * 4 + r;
            const int addr =
                row * 512 + (((col >> 3) ^ (row & 7)) << 3) + (col & 7);
            sigL[addr] = f2bf(fast_tanh(unpackf(drv[i][j][r]) + acc[i][j][r]));
          }
        }
      __syncthreads();
    } else {
#pragma unroll
      for (int i = 0; i < 4; ++i)
#pragma unroll
        for (int j = 0; j < 4; ++j) {
          const int col = w * 64 + j * 16 + l16;
#pragma unroll
          for (int r = 0; r < 4; ++r) {
            const int row = bm * 64 + i * 16 + quad * 4 + r;
            out[(size_t)row * A_DIM + col] =
                fast_tanh(unpackf(drv[i][j][r]) + acc[i][j][r]);
          }
        }
    }
  }
}

extern "C" void kernel_launch(void* const* d_in, const int* in_sizes, int n_in,
                              void* d_out, int out_size, void* d_ws, size_t ws_size,
                              hipStream_t stream) {
  const float* x = (const float*)d_in[0];
  const float* W = (const float*)d_in[1];
  const float* b = (const float*)d_in[2];
  const float* J = (const float*)d_in[3];
  float* out = (float*)d_out;

  char* ws = (char*)d_ws;
  float* drive        = (float*)(ws);                      // 33,554,432 B
  unsigned short* Whi = (unsigned short*)(ws + 33554432);  //  1,048,576 B
  unsigned short* Wlo = (unsigned short*)(ws + 34603008);  //  1,048,576 B
  unsigned short* Jhi = (unsigned short*)(ws + 35651584);  //    524,288 B
  unsigned short* Jlo = (unsigned short*)(ws + 36175872);  // end 36,700,160

  const int nW = A_DIM * M_DIM;
  const int nJ = A_DIM * A_DIM;
  split_kernel<<<(nW + 255) / 256, 256, 0, stream>>>(W, Whi, Wlo, nW, 1.0f);
  split_kernel<<<(nJ + 255) / 256, 256, 0, stream>>>(J, Jhi, Jlo, nJ, 10.0f);

  dim3 grid(A_DIM / 128, B_DIM / 128);  // (4, 128)
  drive_kernel<<<grid, 256, 0, stream>>>(x, Whi, Wlo, b, drive);

  settle_kernel<<<B_DIM / 64, 512, 0, stream>>>(drive, Jhi, Jlo, out);
}

// Round 6
// 615.821 us; speedup vs baseline: 2.2561x; 1.6674x over previous
//
#include <hip/hip_runtime.h>
#include <stdint.h>

// AttractorDynamics: sigma = iterate(tanh(drive + (sigma @ J^T)/tau), 10)
// B=16384, M=1024, A=512, tau=0.1, sigma0=0.
// R6: settle redesigned so per-thread state PROVABLY fits (R4/R5 spilled drv).
//  - 32-row stripes, 512 blocks x 512 threads: drv 32 f32/thread, acc 32.
//  - f16 settling: sigma f16 in 32KB XOR-swizzled LDS, J single f16 (halves
//    L2 traffic and MFMA count vs bf16 hi/lo; err ~1.4e-4/step, under sigma
//    rounding). Drive exact f32 in regs. drive_kernel unchanged (bf16 3-term).

#define B_DIM 16384
#define M_DIM 1024
#define A_DIM 512

typedef short bf16x8 __attribute__((ext_vector_type(8)));
typedef _Float16 f16x8 __attribute__((ext_vector_type(8)));
typedef float f32x4 __attribute__((ext_vector_type(4)));

__device__ __forceinline__ unsigned short f2bf(float f) {
  unsigned int u = __float_as_uint(f);
  unsigned int r = (u + 0x7FFFu + ((u >> 16) & 1u)) >> 16;  // RNE
  return (unsigned short)r;
}
__device__ __forceinline__ float bf2f(unsigned short s) {
  return __uint_as_float(((unsigned int)s) << 16);
}
__device__ __forceinline__ float fast_tanh(float x) {
  float t = __expf(2.0f * x);
  return fmaf(-2.0f, __builtin_amdgcn_rcpf(t + 1.0f), 1.0f);
}

// ---- prep: split fp32 -> bf16 hi + bf16 lo (for W) ----
__global__ void split_kernel(const float* __restrict__ src,
                             unsigned short* __restrict__ hi,
                             unsigned short* __restrict__ lo,
                             int n, float scale) {
  int i = blockIdx.x * 256 + threadIdx.x;
  if (i < n) {
    float v = src[i] * scale;
    unsigned short h = f2bf(v);
    hi[i] = h;
    lo[i] = f2bf(v - bf2f(h));
  }
}

// ---- prep: J/tau -> single f16 ----
__global__ void j16_kernel(const float* __restrict__ src,
                           _Float16* __restrict__ dst, int n, float scale) {
  int i = blockIdx.x * 256 + threadIdx.x;
  if (i < n) dst[i] = (_Float16)(src[i] * scale);
}

// ---- drive GEMM (R1 structure, unchanged): drive = x@W^T + b ----
__global__ __launch_bounds__(256) void drive_kernel(
    const float* __restrict__ x, const unsigned short* __restrict__ Whi,
    const unsigned short* __restrict__ Wlo, const float* __restrict__ bias,
    float* __restrict__ drive) {
  __shared__ __align__(16) unsigned short Ah[128][40];
  __shared__ __align__(16) unsigned short Al[128][40];
  __shared__ __align__(16) unsigned short Bh[128][40];
  __shared__ __align__(16) unsigned short Bl[128][40];

  const int t = threadIdx.x;
  const int bm = blockIdx.y, bn = blockIdx.x;
  const int row = t >> 1, half = t & 1;
  const int lane = t & 63, wave = t >> 6;
  const int wm = wave >> 1, wn = wave & 1;
  const int quad = lane >> 4, l16 = lane & 15;

  f32x4 acc[4][4] = {};

  const float* xp = x + (size_t)(bm * 128 + row) * M_DIM + half * 16;
  const unsigned short* wh = Whi + (size_t)(bn * 128 + row) * M_DIM + half * 16;
  const unsigned short* wl = Wlo + (size_t)(bn * 128 + row) * M_DIM + half * 16;

  for (int k0 = 0; k0 < M_DIM; k0 += 32) {
    float4 v[4];
#pragma unroll
    for (int q = 0; q < 4; ++q) v[q] = *(const float4*)(xp + k0 + 4 * q);
    unsigned short hiv[16], lov[16];
#pragma unroll
    for (int q = 0; q < 4; ++q) {
      float fv[4] = {v[q].x, v[q].y, v[q].z, v[q].w};
#pragma unroll
      for (int e = 0; e < 4; ++e) {
        unsigned short h = f2bf(fv[e]);
        hiv[4 * q + e] = h;
        lov[4 * q + e] = f2bf(fv[e] - bf2f(h));
      }
    }
    *(uint4*)&Ah[row][half * 16]     = *(uint4*)&hiv[0];
    *(uint4*)&Ah[row][half * 16 + 8] = *(uint4*)&hiv[8];
    *(uint4*)&Al[row][half * 16]     = *(uint4*)&lov[0];
    *(uint4*)&Al[row][half * 16 + 8] = *(uint4*)&lov[8];
    *(uint4*)&Bh[row][half * 16]     = *(const uint4*)(wh + k0);
    *(uint4*)&Bh[row][half * 16 + 8] = *(const uint4*)(wh + k0 + 8);
    *(uint4*)&Bl[row][half * 16]     = *(const uint4*)(wl + k0);
    *(uint4*)&Bl[row][half * 16 + 8] = *(const uint4*)(wl + k0 + 8);
    __syncthreads();

    bf16x8 ah[4], al[4], bh[4], bl[4];
#pragma unroll
    for (int i = 0; i < 4; ++i) {
      ah[i] = *(const bf16x8*)&Ah[wm * 64 + i * 16 + l16][quad * 8];
      al[i] = *(const bf16x8*)&Al[wm * 64 + i * 16 + l16][quad * 8];
    }
#pragma unroll
    for (int j = 0; j < 4; ++j) {
      bh[j] = *(const bf16x8*)&Bh[wn * 64 + j * 16 + l16][quad * 8];
      bl[j] = *(const bf16x8*)&Bl[wn * 64 + j * 16 + l16][quad * 8];
    }
#pragma unroll
    for (int i = 0; i < 4; ++i)
#pragma unroll
      for (int j = 0; j < 4; ++j) {
        acc[i][j] = __builtin_amdgcn_mfma_f32_16x16x32_bf16(ah[i], bh[j], acc[i][j], 0, 0, 0);
        acc[i][j] = __builtin_amdgcn_mfma_f32_16x16x32_bf16(ah[i], bl[j], acc[i][j], 0, 0, 0);
        acc[i][j] = __builtin_amdgcn_mfma_f32_16x16x32_bf16(al[i], bh[j], acc[i][j], 0, 0, 0);
      }
    __syncthreads();
  }

#pragma unroll
  for (int i = 0; i < 4; ++i)
#pragma unroll
    for (int j = 0; j < 4; ++j) {
      int gcol = bn * 128 + wn * 64 + j * 16 + l16;
      float bv = bias[gcol];
#pragma unroll
      for (int r = 0; r < 4; ++r) {
        int grow = bm * 128 + wm * 64 + i * 16 + quad * 4 + r;
        drive[(size_t)grow * A_DIM + gcol] = acc[i][j][r] + bv;
      }
    }
}

// ---- settle: 10 steps fused, f16. 512 thr (8 waves), 32-row stripe;
// wave w owns cols [w*64,+64): m-tiles i=0..1, n-tiles j=0..3.
// sigma f16 in XOR-swizzled LDS (granule=8 elems): phys addr =
// row*512 + (((col>>3)^(row&7))<<3) + (col&7). J f16 streamed from L2. ----
__global__ __launch_bounds__(512, 2) void settle_kernel(
    const float* __restrict__ drive, const _Float16* __restrict__ Jf,
    float* __restrict__ out) {
  __shared__ __align__(16) _Float16 sigL[32 * 512];  // 32 KB

  const int t = threadIdx.x;
  const int bm = blockIdx.x;             // rows [bm*32, +32)
  const int lane = t & 63, w = t >> 6;   // 8 waves
  const int quad = lane >> 4, l16 = lane & 15;

  float drv[2][4][4];  // 32 f32, C-layout, lives all 10 steps
  f32x4 acc[2][4];

  // one-time drive load (C-layout) + sigma1 = tanh(drive) -> LDS
#pragma unroll
  for (int i = 0; i < 2; ++i)
#pragma unroll
    for (int j = 0; j < 4; ++j) {
      const int col = w * 64 + j * 16 + l16;
#pragma unroll
      for (int r = 0; r < 4; ++r) {
        const int row = i * 16 + quad * 4 + r;
        float dv = drive[(size_t)(bm * 32 + row) * A_DIM + col];
        drv[i][j][r] = dv;
        sigL[row * 512 + (((col >> 3) ^ (row & 7)) << 3) + (col & 7)] =
            (_Float16)fast_tanh(dv);
      }
    }
  __syncthreads();

  const _Float16* jp = Jf + (size_t)(w * 64 + l16) * A_DIM + quad * 8;

  for (int s = 0; s < 9; ++s) {
#pragma unroll
    for (int i = 0; i < 2; ++i)
#pragma unroll
      for (int j = 0; j < 4; ++j) acc[i][j] = (f32x4){0.f, 0.f, 0.f, 0.f};

#pragma unroll
    for (int c = 0; c < A_DIM / 32; ++c) {  // 16 k-chunks of 32
      f16x8 af[2];
#pragma unroll
      for (int i = 0; i < 2; ++i)
        af[i] = *(const f16x8*)&sigL[(i * 16 + l16) * 512 +
                                     (((c * 4 + quad) ^ (l16 & 7)) << 3)];
      f16x8 bh[4];
#pragma unroll
      for (int j = 0; j < 4; ++j)
        bh[j] = *(const f16x8*)(jp + j * 16 * A_DIM + c * 32);
#pragma unroll
      for (int j = 0; j < 4; ++j)
#pragma unroll
        for (int i = 0; i < 2; ++i)
          acc[i][j] = __builtin_amdgcn_mfma_f32_16x16x32_f16(af[i], bh[j], acc[i][j], 0, 0, 0);
    }

    if (s < 8) {
      __syncthreads();  // all waves done reading sigma_t
#pragma unroll
      for (int i = 0; i < 2; ++i)
#pragma unroll
        for (int j = 0; j < 4; ++j) {
          const int col = w * 64 + j * 16 + l16;
#pragma unroll
          for (int r = 0; r < 4; ++r) {
            const int row = i * 16 + quad * 4 + r;
            sigL[row * 512 + (((col >> 3) ^ (row & 7)) << 3) + (col & 7)] =
                (_Float16)fast_tanh(drv[i][j][r] + acc[i][j][r]);
          }
        }
      __syncthreads();
    } else {
#pragma unroll
      for (int i = 0; i < 2; ++i)
#pragma unroll
        for (int j = 0; j < 4; ++j) {
          const int col = w * 64 + j * 16 + l16;
#pragma unroll
          for (int r = 0; r < 4; ++r) {
            const int row = bm * 32 + i * 16 + quad * 4 + r;
            out[(size_t)row * A_DIM + col] =
                fast_tanh(drv[i][j][r] + acc[i][j][r]);
          }
        }
    }
  }
}

extern "C" void kernel_launch(void* const* d_in, const int* in_sizes, int n_in,
                              void* d_out, int out_size, void* d_ws, size_t ws_size,
                              hipStream_t stream) {
  const float* x = (const float*)d_in[0];
  const float* W = (const float*)d_in[1];
  const float* b = (const float*)d_in[2];
  const float* J = (const float*)d_in[3];
  float* out = (float*)d_out;

  char* ws = (char*)d_ws;
  float* drive        = (float*)(ws);                      // 33,554,432 B
  unsigned short* Whi = (unsigned short*)(ws + 33554432);  //  1,048,576 B
  unsigned short* Wlo = (unsigned short*)(ws + 34603008);  //  1,048,576 B
  _Float16* Jf        = (_Float16*)(ws + 35651584);        //    524,288 B

  const int nW = A_DIM * M_DIM;
  const int nJ = A_DIM * A_DIM;
  split_kernel<<<(nW + 255) / 256, 256, 0, stream>>>(W, Whi, Wlo, nW, 1.0f);
  j16_kernel<<<(nJ + 255) / 256, 256, 0, stream>>>(J, Jf, nJ, 10.0f);

  dim3 grid(A_DIM / 128, B_DIM / 128);  // (4, 128)
  drive_kernel<<<grid, 256, 0, stream>>>(x, Whi, Wlo, b, drive);

  settle_kernel<<<B_DIM / 32, 512, 0, stream>>>(drive, Jf, out);
}